// Round 1
// baseline (404.539 us; speedup 1.0000x reference)
//
#include <hip/hip_runtime.h>
#include <hip/hip_bf16.h>

#define IN_DIM 256
#define OUT_DIM 64

typedef short bf16x8 __attribute__((ext_vector_type(8)));
typedef float f32x4 __attribute__((ext_vector_type(4)));

__device__ inline unsigned short f2bf(float x) {
  unsigned int u = __float_as_uint(x);
  return (unsigned short)((u + 0x7FFFu + ((u >> 16) & 1u)) >> 16);
}

// ---- prep: W [256][64] fp32 -> Wbf in MFMA-fragment-major bf16 -------------
// frag f = (kc,ct,lane): Wbf[f*8 + j] = W[kc*32+(lane>>4)*8+j][ct*16+(lane&15)]
__global__ __launch_bounds__(256) void k_prep(const float* __restrict__ W,
                                              unsigned short* __restrict__ Wbf) {
  int f = blockIdx.x * 256 + threadIdx.x;  // 0..2047
  int kc = f >> 8, ct = (f >> 6) & 3, q = (f >> 4) & 3, nq = f & 15;
  int col = ct * 16 + nq, k0 = kc * 32 + q * 8;
  unsigned short v[8];
#pragma unroll
  for (int j = 0; j < 8; ++j) v[j] = f2bf(W[(size_t)(k0 + j) * OUT_DIM + col]);
  *(uint4*)(Wbf + (size_t)f * 8) = *(uint4*)v;
}

// ---- GEMM: zb(bf16) = h @ W ; el = z@a1 ; er = z@a2 ; + fused deg-histogram -
// 256 thr = 4 waves, 64 rows/block. A staged in LDS via coalesced float4 reads;
// W fragments read directly from frag-major global (L2-hot 32 KB).
// Tail: each thread histograms 4 edges' dst into cur[] (atomic, non-returning).
__global__ __launch_bounds__(256) void k_gemm(const float* __restrict__ h,
                                              const unsigned short* __restrict__ Wbf,
                                              const float* __restrict__ a,
                                              unsigned short* __restrict__ zb,
                                              float* __restrict__ el,
                                              float* __restrict__ er, int n,
                                              const int* __restrict__ dst,
                                              int* __restrict__ cur, int E) {
  __shared__ unsigned short Ab[64][264];  // 33 KB; +8 pad keeps writes 2-way max
  const int t = threadIdx.x;
  const int base = blockIdx.x * 64;

  // stage h tile: 64 rows x 256 cols, 4096 float4, 16/thread, lane-contiguous.
#pragma unroll
  for (int i = 0; i < 16; ++i) {
    int f = i * 256 + t;
    int r = f >> 6, c4 = f & 63;
    int row = base + r;
    float4 v = make_float4(0.f, 0.f, 0.f, 0.f);
    if (row < n) v = *(const float4*)(h + (size_t)row * IN_DIM + c4 * 4);
    unsigned int p0 = (unsigned int)f2bf(v.x) | ((unsigned int)f2bf(v.y) << 16);
    unsigned int p1 = (unsigned int)f2bf(v.z) | ((unsigned int)f2bf(v.w) << 16);
    *(uint2*)&Ab[r][c4 * 4] = make_uint2(p0, p1);
  }
  __syncthreads();

  const int w = t >> 6, lane = t & 63, nq = lane & 15, q = lane >> 4;

  f32x4 acc[4];
#pragma unroll
  for (int ct = 0; ct < 4; ++ct) acc[ct] = (f32x4){0.f, 0.f, 0.f, 0.f};

#pragma unroll
  for (int kc = 0; kc < 8; ++kc) {
    bf16x8 af = *(const bf16x8*)&Ab[w * 16 + nq][kc * 32 + q * 8];
#pragma unroll
    for (int ct = 0; ct < 4; ++ct) {
      bf16x8 bfr = *(const bf16x8*)(Wbf + (size_t)((kc * 4 + ct) * 64 + lane) * 8);
      acc[ct] = __builtin_amdgcn_mfma_f32_16x16x32_bf16(af, bfr, acc[ct], 0, 0, 0);
    }
  }

  // epilogue. C/D: col = ct*16 + nq, row-in-tile = q*4 + r.
  float a1[4], a2[4];
#pragma unroll
  for (int ct = 0; ct < 4; ++ct) {
    a1[ct] = a[ct * 16 + nq];
    a2[ct] = a[OUT_DIM + ct * 16 + nq];
  }
#pragma unroll
  for (int r = 0; r < 4; ++r) {
    int orow = base + w * 16 + q * 4 + r;
    float p1 = 0.f, p2 = 0.f;
#pragma unroll
    for (int ct = 0; ct < 4; ++ct) {
      float v = acc[ct][r];
      p1 += v * a1[ct];
      p2 += v * a2[ct];
      if (orow < n) zb[(size_t)orow * OUT_DIM + ct * 16 + nq] = f2bf(v);
    }
    p1 += __shfl_xor(p1, 1); p1 += __shfl_xor(p1, 2);
    p1 += __shfl_xor(p1, 4); p1 += __shfl_xor(p1, 8);
    p2 += __shfl_xor(p2, 1); p2 += __shfl_xor(p2, 2);
    p2 += __shfl_xor(p2, 4); p2 += __shfl_xor(p2, 8);
    if (orow < n && nq == 0) { el[orow] = p1; er[orow] = p2; }
  }

  // fused degree histogram: this grid covers E at 4 edges/thread.
  int e0 = blockIdx.x * 1024 + t * 4;
  if (e0 + 4 <= E) {
    int4 d4 = *(const int4*)(dst + e0);
    atomicAdd(&cur[d4.x], 1);
    atomicAdd(&cur[d4.y], 1);
    atomicAdd(&cur[d4.z], 1);
    atomicAdd(&cur[d4.w], 1);
  } else {
#pragma unroll
    for (int k = 0; k < 4; ++k) {
      int e = e0 + k;
      if (e < E) atomicAdd(&cur[dst[e]], 1);
    }
  }
}

// ------------- generic scan: per-block (1024) exclusive + block totals -------
__global__ __launch_bounds__(256) void k_scanA(const int* __restrict__ in,
                                               int* __restrict__ out,
                                               int* __restrict__ bsum, int N) {
  __shared__ int wtot[4];
  int t = threadIdx.x, lane = t & 63, w = t >> 6;
  int idx = blockIdx.x * 1024 + t * 4;
  int d0 = idx + 0 < N ? in[idx + 0] : 0;
  int d1 = idx + 1 < N ? in[idx + 1] : 0;
  int d2 = idx + 2 < N ? in[idx + 2] : 0;
  int d3 = idx + 3 < N ? in[idx + 3] : 0;
  int tsum = d0 + d1 + d2 + d3;
  int incl = tsum;
  for (int o = 1; o < 64; o <<= 1) {
    int v = __shfl_up(incl, o);
    if (lane >= o) incl += v;
  }
  if (lane == 63) wtot[w] = incl;
  __syncthreads();
  int woff = 0;
  for (int i = 0; i < 4; ++i)
    if (i < w) woff += wtot[i];
  int btot = wtot[0] + wtot[1] + wtot[2] + wtot[3];
  int e = woff + incl - tsum;
  if (idx + 0 < N) out[idx + 0] = e; e += d0;
  if (idx + 1 < N) out[idx + 1] = e; e += d1;
  if (idx + 2 < N) out[idx + 2] = e; e += d2;
  if (idx + 3 < N) out[idx + 3] = e;
  if (t == 0) bsum[blockIdx.x] = btot;
}

__global__ __launch_bounds__(256) void k_scanB(int* __restrict__ bsum, int nb) {
  __shared__ int wtot[4];
  int t = threadIdx.x, lane = t & 63, w = t >> 6;
  int v = t < nb ? bsum[t] : 0;
  int incl = v;
  for (int o = 1; o < 64; o <<= 1) {
    int u = __shfl_up(incl, o);
    if (lane >= o) incl += u;
  }
  if (lane == 63) wtot[w] = incl;
  __syncthreads();
  int woff = 0;
  for (int i = 0; i < 4; ++i)
    if (i < w) woff += wtot[i];
  if (t < nb) bsum[t] = woff + incl - v;
}

// fixup + seed cur[] with the absolute base so the scatter needs ONE atomic.
__global__ __launch_bounds__(256) void k_scanC2(int* __restrict__ out,
                                                const int* __restrict__ bsum,
                                                int* __restrict__ cur, int M) {
  int i = blockIdx.x * 256 + threadIdx.x;
  if (i < M) {
    int v = out[i] + bsum[i >> 10];
    out[i] = v;
    cur[i] = v;
  }
}

// ------------- CSR scatter: ssrc[atomicAdd(cur[dst])] = src -----------------
// Order within a node is nondeterministic; aggregation is a sum, so fine.
__global__ __launch_bounds__(256) void k_scat(const int* __restrict__ src,
                                              const int* __restrict__ dst,
                                              int* __restrict__ cur,
                                              int* __restrict__ ssrc, int E) {
  int e0 = (blockIdx.x * 256 + threadIdx.x) * 4;
  if (e0 + 4 <= E) {
    int4 s4 = *(const int4*)(src + e0);
    int4 d4 = *(const int4*)(dst + e0);
    ssrc[atomicAdd(&cur[d4.x], 1)] = s4.x;
    ssrc[atomicAdd(&cur[d4.y], 1)] = s4.y;
    ssrc[atomicAdd(&cur[d4.z], 1)] = s4.z;
    ssrc[atomicAdd(&cur[d4.w], 1)] = s4.w;
  } else {
#pragma unroll
    for (int k = 0; k < 4; ++k) {
      int e = e0 + k;
      if (e < E) ssrc[atomicAdd(&cur[dst[e]], 1)] = src[e];
    }
  }
}

// ------- fused aggregate: x4-unrolled gather for MLP --------------------------
__global__ __launch_bounds__(256) void k_agg(const int* __restrict__ off,
                                             const int* __restrict__ ssrc,
                                             const float* __restrict__ el,
                                             const float* __restrict__ er,
                                             const unsigned short* __restrict__ zb,
                                             float* __restrict__ out, int N) {
  int t = threadIdx.x;
  int node = blockIdx.x * 16 + (t >> 4);
  if (node >= N) return;
  int cq = (t & 15) * 4;
  int beg = off[node], end = off[node + 1];
  float erd = er[node];
  float ax = 0.f, ay = 0.f, az = 0.f, aw = 0.f, ssum = 0.f;
  int j = beg;
  for (; j + 4 <= end; j += 4) {
    int s0 = ssrc[j], s1 = ssrc[j + 1], s2 = ssrc[j + 2], s3 = ssrc[j + 3];
    uint2 z0 = *(const uint2*)(zb + (s0 << 6) + cq);
    uint2 z1 = *(const uint2*)(zb + (s1 << 6) + cq);
    uint2 z2 = *(const uint2*)(zb + (s2 << 6) + cq);
    uint2 z3 = *(const uint2*)(zb + (s3 << 6) + cq);
    float x0 = el[s0] + erd, x1 = el[s1] + erd;
    float x2 = el[s2] + erd, x3 = el[s3] + erd;
    x0 = x0 > 0.f ? x0 : 0.01f * x0;
    x1 = x1 > 0.f ? x1 : 0.01f * x1;
    x2 = x2 > 0.f ? x2 : 0.01f * x2;
    x3 = x3 > 0.f ? x3 : 0.01f * x3;
    float e0 = __expf(x0), e1 = __expf(x1), e2 = __expf(x2), e3 = __expf(x3);
    ssum += (e0 + e1) + (e2 + e3);
    ax += e0 * __uint_as_float(z0.x << 16) + e1 * __uint_as_float(z1.x << 16) +
          e2 * __uint_as_float(z2.x << 16) + e3 * __uint_as_float(z3.x << 16);
    ay += e0 * __uint_as_float(z0.x & 0xFFFF0000u) + e1 * __uint_as_float(z1.x & 0xFFFF0000u) +
          e2 * __uint_as_float(z2.x & 0xFFFF0000u) + e3 * __uint_as_float(z3.x & 0xFFFF0000u);
    az += e0 * __uint_as_float(z0.y << 16) + e1 * __uint_as_float(z1.y << 16) +
          e2 * __uint_as_float(z2.y << 16) + e3 * __uint_as_float(z3.y << 16);
    aw += e0 * __uint_as_float(z0.y & 0xFFFF0000u) + e1 * __uint_as_float(z1.y & 0xFFFF0000u) +
          e2 * __uint_as_float(z2.y & 0xFFFF0000u) + e3 * __uint_as_float(z3.y & 0xFFFF0000u);
  }
  for (; j < end; ++j) {
    int s = ssrc[j];
    uint2 zv = *(const uint2*)(zb + (s << 6) + cq);
    float x = el[s] + erd;
    x = x > 0.f ? x : 0.01f * x;
    float ex = __expf(x);
    ssum += ex;
    ax += ex * __uint_as_float(zv.x << 16);
    ay += ex * __uint_as_float(zv.x & 0xFFFF0000u);
    az += ex * __uint_as_float(zv.y << 16);
    aw += ex * __uint_as_float(zv.y & 0xFFFF0000u);
  }
  float4 o = make_float4(0.f, 0.f, 0.f, 0.f);
  if (end > beg) {
    float inv = 1.f / ssum;
    ax *= inv; ay *= inv; az *= inv; aw *= inv;
    o.x = ax > 0.f ? ax : __expf(ax) - 1.f;
    o.y = ay > 0.f ? ay : __expf(ay) - 1.f;
    o.z = az > 0.f ? az : __expf(az) - 1.f;
    o.w = aw > 0.f ? aw : __expf(aw) - 1.f;
  }
  *(float4*)(out + ((size_t)node << 6) + cq) = o;
}

extern "C" void kernel_launch(void* const* d_in, const int* in_sizes, int n_in,
                              void* d_out, int out_size, void* d_ws, size_t ws_size,
                              hipStream_t stream) {
  const float* h = (const float*)d_in[0];
  const float* W = (const float*)d_in[1];
  const float* a = (const float*)d_in[2];
  const int* src = (const int*)d_in[3];
  const int* dst = (const int*)d_in[4];
  const int n = in_sizes[0] / IN_DIM;  // 100000
  const int E = in_sizes[3];           // 1600000
  float* out = (float*)d_out;

  char* ws = (char*)d_ws;
  auto alloc = [&](size_t bytes) {
    char* p = ws;
    ws += (bytes + 15) & ~(size_t)15;
    return p;
  };
  unsigned short* Wbf = (unsigned short*)alloc(16384 * 2);
  unsigned short* zb = (unsigned short*)alloc((size_t)n * OUT_DIM * 2);
  float* el = (float*)alloc((size_t)n * 4);
  float* er = (float*)alloc((size_t)n * 4);
  int* off = (int*)alloc((size_t)(n + 1) * 4);
  int* cur = (int*)alloc((size_t)(n + 1) * 4);
  int* bsum = (int*)alloc(256 * 4);
  int* ssrc = (int*)alloc((size_t)E * 4);

  const int M = n + 1;                    // scan length (off[n] = E)
  const int NB = (M + 1023) / 1024;       // 98 scan blocks
  const int gemm_blocks = (n + 63) / 64;  // 1563; also covers E at 4 edges/thr
  const int edge_blocks = (E + 1023) / 1024;
  const int gb = gemm_blocks > edge_blocks ? gemm_blocks : edge_blocks;

  hipMemsetAsync(cur, 0, (size_t)M * 4, stream);
  k_prep<<<8, 256, 0, stream>>>(W, Wbf);
  k_gemm<<<gb, 256, 0, stream>>>(h, Wbf, a, zb, el, er, n, dst, cur, E);
  k_scanA<<<NB, 256, 0, stream>>>(cur, off, bsum, M);
  k_scanB<<<1, 256, 0, stream>>>(bsum, NB);
  k_scanC2<<<(M + 255) / 256, 256, 0, stream>>>(off, bsum, cur, M);
  k_scat<<<edge_blocks, 256, 0, stream>>>(src, dst, cur, ssrc, E);
  k_agg<<<(n + 15) / 16, 256, 0, stream>>>(off, ssrc, el, er, zb, out, n);
}

// Round 2
// 261.343 us; speedup vs baseline: 1.5479x; 1.5479x over previous
//
#include <hip/hip_runtime.h>
#include <hip/hip_bf16.h>

#define IN_DIM 256
#define OUT_DIM 64
#define CHUNK 4096
#define BSH 8      // bucket = dst >> 8 (256 nodes/bucket)
#define P2CAP 6144

typedef short bf16x8 __attribute__((ext_vector_type(8)));
typedef float f32x4 __attribute__((ext_vector_type(4)));

__device__ inline unsigned short f2bf(float x) {
  unsigned int u = __float_as_uint(x);
  return (unsigned short)((u + 0x7FFFu + ((u >> 16) & 1u)) >> 16);
}

// ---- prep: W [256][64] fp32 -> Wbf in MFMA-fragment-major bf16 -------------
// frag f = (kc,ct,lane): Wbf[f*8 + j] = W[kc*32+(lane>>4)*8+j][ct*16+(lane&15)]
__global__ __launch_bounds__(256) void k_prep(const float* __restrict__ W,
                                              unsigned short* __restrict__ Wbf) {
  int f = blockIdx.x * 256 + threadIdx.x;  // 0..2047
  int kc = f >> 8, ct = (f >> 6) & 3, q = (f >> 4) & 3, nq = f & 15;
  int col = ct * 16 + nq, k0 = kc * 32 + q * 8;
  unsigned short v[8];
#pragma unroll
  for (int j = 0; j < 8; ++j) v[j] = f2bf(W[(size_t)(k0 + j) * OUT_DIM + col]);
  *(uint4*)(Wbf + (size_t)f * 8) = *(uint4*)v;
}

// ---- GEMM: zb(bf16) = h @ W ; el = z@a1 ; er = z@a2 -------------------------
// 256 thr = 4 waves, 64 rows/block. A staged in LDS via coalesced float4 reads;
// W fragments read directly from frag-major global (L2-hot 32 KB).
// Tail (blocks < b1): per-chunk per-bucket histogram -> gh (bucket-major),
// hidden under the GEMM stream (dst read coalesces with h stream in HBM).
__global__ __launch_bounds__(256) void k_gemm(const float* __restrict__ h,
                                              const unsigned short* __restrict__ Wbf,
                                              const float* __restrict__ a,
                                              unsigned short* __restrict__ zb,
                                              float* __restrict__ el,
                                              float* __restrict__ er, int n,
                                              const int* __restrict__ dst,
                                              int* __restrict__ gh, int E,
                                              int nbuck, int b1) {
  __shared__ unsigned short Ab[64][264];  // 33 KB; +8 pad keeps writes 2-way max
  __shared__ int hist[512];
  const int t = threadIdx.x;
  const int base = blockIdx.x * 64;

  // stage h tile: 64 rows x 256 cols, 4096 float4, 16/thread, lane-contiguous.
#pragma unroll
  for (int i = 0; i < 16; ++i) {
    int f = i * 256 + t;
    int r = f >> 6, c4 = f & 63;
    int row = base + r;
    float4 v = make_float4(0.f, 0.f, 0.f, 0.f);
    if (row < n) v = *(const float4*)(h + (size_t)row * IN_DIM + c4 * 4);
    unsigned int p0 = (unsigned int)f2bf(v.x) | ((unsigned int)f2bf(v.y) << 16);
    unsigned int p1 = (unsigned int)f2bf(v.z) | ((unsigned int)f2bf(v.w) << 16);
    *(uint2*)&Ab[r][c4 * 4] = make_uint2(p0, p1);
  }
  __syncthreads();

  const int w = t >> 6, lane = t & 63, nq = lane & 15, q = lane >> 4;

  f32x4 acc[4];
#pragma unroll
  for (int ct = 0; ct < 4; ++ct) acc[ct] = (f32x4){0.f, 0.f, 0.f, 0.f};

#pragma unroll
  for (int kc = 0; kc < 8; ++kc) {
    bf16x8 af = *(const bf16x8*)&Ab[w * 16 + nq][kc * 32 + q * 8];
#pragma unroll
    for (int ct = 0; ct < 4; ++ct) {
      bf16x8 bfr = *(const bf16x8*)(Wbf + (size_t)((kc * 4 + ct) * 64 + lane) * 8);
      acc[ct] = __builtin_amdgcn_mfma_f32_16x16x32_bf16(af, bfr, acc[ct], 0, 0, 0);
    }
  }

  // epilogue. C/D: col = ct*16 + nq, row-in-tile = q*4 + r.
  float a1[4], a2[4];
#pragma unroll
  for (int ct = 0; ct < 4; ++ct) {
    a1[ct] = a[ct * 16 + nq];
    a2[ct] = a[OUT_DIM + ct * 16 + nq];
  }
#pragma unroll
  for (int r = 0; r < 4; ++r) {
    int orow = base + w * 16 + q * 4 + r;
    float p1 = 0.f, p2 = 0.f;
#pragma unroll
    for (int ct = 0; ct < 4; ++ct) {
      float v = acc[ct][r];
      p1 += v * a1[ct];
      p2 += v * a2[ct];
      if (orow < n) zb[(size_t)orow * OUT_DIM + ct * 16 + nq] = f2bf(v);
    }
    p1 += __shfl_xor(p1, 1); p1 += __shfl_xor(p1, 2);
    p1 += __shfl_xor(p1, 4); p1 += __shfl_xor(p1, 8);
    p2 += __shfl_xor(p2, 1); p2 += __shfl_xor(p2, 2);
    p2 += __shfl_xor(p2, 4); p2 += __shfl_xor(p2, 8);
    if (orow < n && nq == 0) { el[orow] = p1; er[orow] = p2; }
  }

  // fused per-chunk bucket histogram (blocks 0..b1-1 only).
  if (blockIdx.x < b1) {
    hist[t] = 0;
    hist[t + 256] = 0;
    __syncthreads();
    int beg = blockIdx.x * CHUNK;
#pragma unroll
    for (int i = t; i < CHUNK; i += 256) {
      int e = beg + i;
      if (e < E) atomicAdd(&hist[dst[e] >> BSH], 1);
    }
    __syncthreads();
    for (int i = t; i < nbuck; i += 256) gh[i * b1 + blockIdx.x] = hist[i];
  }
}

// ------------- generic scan: per-block (1024) exclusive + block totals -------
__global__ __launch_bounds__(256) void k_scanA(const int* __restrict__ in,
                                               int* __restrict__ out,
                                               int* __restrict__ bsum, int N) {
  __shared__ int wtot[4];
  int t = threadIdx.x, lane = t & 63, w = t >> 6;
  int idx = blockIdx.x * 1024 + t * 4;
  int d0 = idx + 0 < N ? in[idx + 0] : 0;
  int d1 = idx + 1 < N ? in[idx + 1] : 0;
  int d2 = idx + 2 < N ? in[idx + 2] : 0;
  int d3 = idx + 3 < N ? in[idx + 3] : 0;
  int tsum = d0 + d1 + d2 + d3;
  int incl = tsum;
  for (int o = 1; o < 64; o <<= 1) {
    int v = __shfl_up(incl, o);
    if (lane >= o) incl += v;
  }
  if (lane == 63) wtot[w] = incl;
  __syncthreads();
  int woff = 0;
  for (int i = 0; i < 4; ++i)
    if (i < w) woff += wtot[i];
  int btot = wtot[0] + wtot[1] + wtot[2] + wtot[3];
  int e = woff + incl - tsum;
  if (idx + 0 < N) out[idx + 0] = e; e += d0;
  if (idx + 1 < N) out[idx + 1] = e; e += d1;
  if (idx + 2 < N) out[idx + 2] = e; e += d2;
  if (idx + 3 < N) out[idx + 3] = e;
  if (t == 0) bsum[blockIdx.x] = btot;
}

__global__ __launch_bounds__(256) void k_scanB(int* __restrict__ bsum, int nb) {
  __shared__ int wtot[4];
  int t = threadIdx.x, lane = t & 63, w = t >> 6;
  int v = t < nb ? bsum[t] : 0;
  int incl = v;
  for (int o = 1; o < 64; o <<= 1) {
    int u = __shfl_up(incl, o);
    if (lane >= o) incl += u;
  }
  if (lane == 63) wtot[w] = incl;
  __syncthreads();
  int woff = 0;
  for (int i = 0; i < 4; ++i)
    if (i < w) woff += wtot[i];
  if (t < nb) bsum[t] = woff + incl - v;
}

// ------------- pass-1 scatter: partition packed (ldst,src) by bucket ---------
// pairs entry = (dst & 255) << 24 | src   (src < 2^17). bsum fixup fused.
__global__ __launch_bounds__(256) void k_p1scat(const int* __restrict__ src,
                                                const int* __restrict__ dst,
                                                const int* __restrict__ pbase,
                                                const int* __restrict__ bsum,
                                                int* __restrict__ pairs, int E,
                                                int nbuck, int b1) {
  __shared__ int pb[512];
  __shared__ int cur[512];
  int t = threadIdx.x, b = blockIdx.x;
  for (int i = t; i < 512; i += 256) {
    if (i < nbuck) {
      int idx = i * b1 + b;
      pb[i] = pbase[idx] + bsum[idx >> 10];
    } else {
      pb[i] = 0;
    }
    cur[i] = 0;
  }
  __syncthreads();
  int beg = b * CHUNK;
#pragma unroll
  for (int i = t; i < CHUNK; i += 256) {
    int e = beg + i;
    if (e < E) {
      int d = dst[e], s = src[e];
      int bk = d >> BSH;
      int r = atomicAdd(&cur[bk], 1);
      pairs[pb[bk] + r] = ((d & ((1 << BSH) - 1)) << 24) | s;
    }
  }
}

// ------------- pass-2: per-bucket in-LDS counting sort + off[] emit ----------
__global__ __launch_bounds__(256) void k_p2(const int* __restrict__ pairs,
                                            const int* __restrict__ pbase,
                                            const int* __restrict__ bsum,
                                            int* __restrict__ ssrc,
                                            int* __restrict__ off, int E, int n,
                                            int nbuck, int b1) {
  __shared__ int deg[256];
  __shared__ int loff[256];
  __shared__ int cur[256];
  __shared__ int stage[P2CAP];
  __shared__ int wtot[4];
  int t = threadIdx.x, b = blockIdx.x;
  int i0 = b * b1;
  int beg = pbase[i0] + bsum[i0 >> 10];
  int end;
  if (b + 1 < nbuck) {
    int i1 = (b + 1) * b1;
    end = pbase[i1] + bsum[i1 >> 10];
  } else {
    end = E;
  }
  int cnt = end - beg;
  deg[t] = 0;
  __syncthreads();
  for (int i = t; i < cnt; i += 256)
    atomicAdd(&deg[((unsigned)pairs[beg + i]) >> 24], 1);
  __syncthreads();
  int v = deg[t];
  int lane = t & 63, w = t >> 6;
  int inc = v;
  for (int o = 1; o < 64; o <<= 1) {
    int u = __shfl_up(inc, o);
    if (lane >= o) inc += u;
  }
  if (lane == 63) wtot[w] = inc;
  __syncthreads();
  int woff = 0;
  for (int i = 0; i < 4; ++i)
    if (i < w) woff += wtot[i];
  int ex = woff + inc - v;
  loff[t] = ex;
  cur[t] = ex;
  __syncthreads();
  for (int i = t; i < cnt; i += 256) {
    int p = pairs[beg + i];
    int r = atomicAdd(&cur[((unsigned)p) >> 24], 1);
    if (r < P2CAP) stage[r] = p & 0xFFFFFF;
  }
  __syncthreads();
  for (int i = t; i < cnt; i += 256) ssrc[beg + i] = stage[i];
  int node = (b << BSH) + t;
  if (node <= n) off[node] = beg + loff[t];
}

// ------- fused aggregate: x4-unrolled gather for MLP --------------------------
__global__ __launch_bounds__(256) void k_agg(const int* __restrict__ off,
                                             const int* __restrict__ ssrc,
                                             const float* __restrict__ el,
                                             const float* __restrict__ er,
                                             const unsigned short* __restrict__ zb,
                                             float* __restrict__ out, int N) {
  int t = threadIdx.x;
  int node = blockIdx.x * 16 + (t >> 4);
  if (node >= N) return;
  int cq = (t & 15) * 4;
  int beg = off[node], end = off[node + 1];
  float erd = er[node];
  float ax = 0.f, ay = 0.f, az = 0.f, aw = 0.f, ssum = 0.f;
  int j = beg;
  for (; j + 4 <= end; j += 4) {
    int s0 = ssrc[j], s1 = ssrc[j + 1], s2 = ssrc[j + 2], s3 = ssrc[j + 3];
    uint2 z0 = *(const uint2*)(zb + (s0 << 6) + cq);
    uint2 z1 = *(const uint2*)(zb + (s1 << 6) + cq);
    uint2 z2 = *(const uint2*)(zb + (s2 << 6) + cq);
    uint2 z3 = *(const uint2*)(zb + (s3 << 6) + cq);
    float x0 = el[s0] + erd, x1 = el[s1] + erd;
    float x2 = el[s2] + erd, x3 = el[s3] + erd;
    x0 = x0 > 0.f ? x0 : 0.01f * x0;
    x1 = x1 > 0.f ? x1 : 0.01f * x1;
    x2 = x2 > 0.f ? x2 : 0.01f * x2;
    x3 = x3 > 0.f ? x3 : 0.01f * x3;
    float e0 = __expf(x0), e1 = __expf(x1), e2 = __expf(x2), e3 = __expf(x3);
    ssum += (e0 + e1) + (e2 + e3);
    ax += e0 * __uint_as_float(z0.x << 16) + e1 * __uint_as_float(z1.x << 16) +
          e2 * __uint_as_float(z2.x << 16) + e3 * __uint_as_float(z3.x << 16);
    ay += e0 * __uint_as_float(z0.x & 0xFFFF0000u) + e1 * __uint_as_float(z1.x & 0xFFFF0000u) +
          e2 * __uint_as_float(z2.x & 0xFFFF0000u) + e3 * __uint_as_float(z3.x & 0xFFFF0000u);
    az += e0 * __uint_as_float(z0.y << 16) + e1 * __uint_as_float(z1.y << 16) +
          e2 * __uint_as_float(z2.y << 16) + e3 * __uint_as_float(z3.y << 16);
    aw += e0 * __uint_as_float(z0.y & 0xFFFF0000u) + e1 * __uint_as_float(z1.y & 0xFFFF0000u) +
          e2 * __uint_as_float(z2.y & 0xFFFF0000u) + e3 * __uint_as_float(z3.y & 0xFFFF0000u);
  }
  for (; j < end; ++j) {
    int s = ssrc[j];
    uint2 zv = *(const uint2*)(zb + (s << 6) + cq);
    float x = el[s] + erd;
    x = x > 0.f ? x : 0.01f * x;
    float ex = __expf(x);
    ssum += ex;
    ax += ex * __uint_as_float(zv.x << 16);
    ay += ex * __uint_as_float(zv.x & 0xFFFF0000u);
    az += ex * __uint_as_float(zv.y << 16);
    aw += ex * __uint_as_float(zv.y & 0xFFFF0000u);
  }
  float4 o = make_float4(0.f, 0.f, 0.f, 0.f);
  if (end > beg) {
    float inv = 1.f / ssum;
    ax *= inv; ay *= inv; az *= inv; aw *= inv;
    o.x = ax > 0.f ? ax : __expf(ax) - 1.f;
    o.y = ay > 0.f ? ay : __expf(ay) - 1.f;
    o.z = az > 0.f ? az : __expf(az) - 1.f;
    o.w = aw > 0.f ? aw : __expf(aw) - 1.f;
  }
  *(float4*)(out + ((size_t)node << 6) + cq) = o;
}

extern "C" void kernel_launch(void* const* d_in, const int* in_sizes, int n_in,
                              void* d_out, int out_size, void* d_ws, size_t ws_size,
                              hipStream_t stream) {
  const float* h = (const float*)d_in[0];
  const float* W = (const float*)d_in[1];
  const float* a = (const float*)d_in[2];
  const int* src = (const int*)d_in[3];
  const int* dst = (const int*)d_in[4];
  const int n = in_sizes[0] / IN_DIM;  // 100000
  const int E = in_sizes[3];           // 1600000
  float* out = (float*)d_out;

  const int b1 = (E + CHUNK - 1) / CHUNK;         // 391
  const int nbuck = (n + (1 << BSH) - 1) >> BSH;  // 391
  const int M = nbuck * b1;                       // 152881
  const int NB = (M + 1023) / 1024;               // 150

  char* ws = (char*)d_ws;
  auto alloc = [&](size_t bytes) {
    char* p = ws;
    ws += (bytes + 15) & ~(size_t)15;
    return p;
  };
  unsigned short* Wbf = (unsigned short*)alloc(16384 * 2);
  unsigned short* zb = (unsigned short*)alloc((size_t)n * OUT_DIM * 2);
  float* el = (float*)alloc((size_t)n * 4);
  float* er = (float*)alloc((size_t)n * 4);
  int* gh = (int*)alloc((size_t)M * 4);
  int* pbase = (int*)alloc((size_t)M * 4);
  int* bsum = (int*)alloc(256 * 4);
  int* off = (int*)alloc((size_t)(n + 1) * 4);
  int* pairs = (int*)alloc((size_t)E * 4);
  int* ssrc = (int*)alloc((size_t)E * 4);

  k_prep<<<8, 256, 0, stream>>>(W, Wbf);
  k_gemm<<<(n + 63) / 64, 256, 0, stream>>>(h, Wbf, a, zb, el, er, n, dst, gh, E, nbuck, b1);
  k_scanA<<<NB, 256, 0, stream>>>(gh, pbase, bsum, M);
  k_scanB<<<1, 256, 0, stream>>>(bsum, NB);
  k_p1scat<<<b1, 256, 0, stream>>>(src, dst, pbase, bsum, pairs, E, nbuck, b1);
  k_p2<<<nbuck, 256, 0, stream>>>(pairs, pbase, bsum, ssrc, off, E, n, nbuck, b1);
  k_agg<<<(n + 15) / 16, 256, 0, stream>>>(off, ssrc, el, er, zb, out, n);
}